// Round 2
// baseline (88.896 us; speedup 1.0000x reference)
//
#include <hip/hip_runtime.h>

#define EPS 1e-8f
#define PANEL_CAP 12850   // max floats of LDS panel (51.4 KB)

// ---------------------------------------------------------------------------
// Pass 1: block = (b, chunk c). Stage contiguous panel mag[b, c*L:(c+1)*L, :]
// into LDS with wide loads, scan each feature chain with carry-in 0, store
// chunk-end summary S_c.
// ---------------------------------------------------------------------------
__global__ __launch_bounds__(256)
void fns2_pass1(const float* __restrict__ mag,
                const float* __restrict__ alpha,
                float* __restrict__ S,   // [C][BF]
                int B, int T, int F, int L, int C) {
    __shared__ float panel[PANEL_CAP];

    int bid = blockIdx.x;
    int b = bid / C;
    int c = bid - b * C;

    int t0 = c * L;
    int t1 = min(t0 + L, T);
    int Lc = t1 - t0;
    int nElem = Lc * F;

    size_t off = ((size_t)b * T + (size_t)t0) * F;

    // ---- stage: contiguous, wide ----
    if ((off & 1) == 0 && (nElem & 1) == 0) {
        const float2* s2 = reinterpret_cast<const float2*>(mag + off);
        float2* p2 = reinterpret_cast<float2*>(panel);
        int n2 = nElem >> 1;
        for (int i = threadIdx.x; i < n2; i += blockDim.x) p2[i] = s2[i];
    } else {
        for (int i = threadIdx.x; i < nElem; i += blockDim.x) panel[i] = mag[off + i];
    }
    __syncthreads();

    // ---- scan chains out of LDS ----
    int BF = B * F;
    for (int f = threadIdx.x; f < F; f += blockDim.x) {
        float a = 1.0f / (1.0f + expf(-alpha[f]));
        float local = 0.0f;
        for (int t = 0; t < Lc; ++t) {
            float m = panel[t * F + f];
            local = local * (1.0f - a) + (m * m) * a;   // exact reference form
        }
        S[(size_t)c * BF + (size_t)b * F + f] = local;
    }
}

// ---------------------------------------------------------------------------
// Pass 3 (pass2 fused): block = (b, chunk c). Each thread reconstructs its
// exact carry-in from s0 and the c preceding chunk summaries, re-stages the
// panel (L3-warm), scans, writes normalized results back into LDS, then
// cooperatively stores the contiguous panel to out.
// ---------------------------------------------------------------------------
__global__ __launch_bounds__(256)
void fns2_pass3(const float* __restrict__ mag,
                const float* __restrict__ s0,
                const float* __restrict__ weights,
                const float* __restrict__ bias,
                const float* __restrict__ alpha,
                const float* __restrict__ S,   // [C][BF] chunk summaries
                float* __restrict__ out,
                int B, int T, int F, int L, int C) {
    __shared__ float panel[PANEL_CAP];

    int bid = blockIdx.x;
    int b = bid / C;
    int c = bid - b * C;

    int t0 = c * L;
    int t1 = min(t0 + L, T);
    int Lc = t1 - t0;
    int nElem = Lc * F;

    size_t off = ((size_t)b * T + (size_t)t0) * F;

    // ---- stage ----
    if ((off & 1) == 0 && (nElem & 1) == 0) {
        const float2* s2 = reinterpret_cast<const float2*>(mag + off);
        float2* p2 = reinterpret_cast<float2*>(panel);
        int n2 = nElem >> 1;
        for (int i = threadIdx.x; i < n2; i += blockDim.x) p2[i] = s2[i];
    } else {
        for (int i = threadIdx.x; i < nElem; i += blockDim.x) panel[i] = mag[off + i];
    }
    __syncthreads();

    int BF = B * F;
    for (int f = threadIdx.x; f < F; f += blockDim.x) {
        float a  = 1.0f / (1.0f + expf(-alpha[f]));
        float w  = weights[f];
        float bi = bias[f];

        // reconstruct carry-in for chunk c (identical arithmetic to a
        // dedicated sequential pass: all preceding chunks have full length L)
        float decay = powf(1.0f - a, (float)L);
        float carry = s0[(size_t)b * F + f];
        for (int j = 0; j < c; ++j) {
            carry = carry * decay + S[(size_t)j * BF + (size_t)b * F + f];
        }

        // scan + normalize, write result back into the same LDS slot
        for (int t = 0; t < Lc; ++t) {
            float m = panel[t * F + f];
            carry = carry * (1.0f - a) + (m * m) * a;
            panel[t * F + f] = m / (sqrtf(carry) + EPS) * w + bi;
        }
    }
    __syncthreads();

    // ---- cooperative contiguous store ----
    if ((off & 1) == 0 && (nElem & 1) == 0) {
        float2* d2 = reinterpret_cast<float2*>(out + off);
        const float2* p2 = reinterpret_cast<const float2*>(panel);
        int n2 = nElem >> 1;
        for (int i = threadIdx.x; i < n2; i += blockDim.x) d2[i] = p2[i];
    } else {
        for (int i = threadIdx.x; i < nElem; i += blockDim.x) out[off + i] = panel[i];
    }
}

// ---------------------------------------------------------------------------
// Fallback: one thread per (b,f) chain (used only if ws too small).
// ---------------------------------------------------------------------------
__global__ void fns2_fallback(const float* __restrict__ mag,
                              const float* __restrict__ s0,
                              const float* __restrict__ weights,
                              const float* __restrict__ bias,
                              const float* __restrict__ alpha,
                              float* __restrict__ out,
                              int B, int T, int F) {
    int bf = blockIdx.x * blockDim.x + threadIdx.x;
    int BF = B * F;
    if (bf >= BF) return;
    int b = bf / F;
    int f = bf - b * F;

    float a  = 1.0f / (1.0f + expf(-alpha[f]));
    float w  = weights[f];
    float bi = bias[f];

    float carry = s0[bf];
    const float* p = mag + (size_t)b * T * F + f;
    float*       o = out + (size_t)b * T * F + f;

    for (int t = 0; t < T; ++t) {
        float m = p[(size_t)t * F];
        carry = carry * (1.0f - a) + (m * m) * a;
        o[(size_t)t * F] = m / (sqrtf(carry) + EPS) * w + bi;
    }
}

extern "C" void kernel_launch(void* const* d_in, const int* in_sizes, int n_in,
                              void* d_out, int out_size, void* d_ws, size_t ws_size,
                              hipStream_t stream) {
    const float* mag     = (const float*)d_in[0];
    const float* s0      = (const float*)d_in[1];
    const float* weights = (const float*)d_in[2];
    const float* bias    = (const float*)d_in[3];
    const float* alpha   = (const float*)d_in[4];
    float* out = (float*)d_out;

    int F  = in_sizes[4];          // alpha is [1, F]
    int BF = in_sizes[1];          // s is [B, F]
    int B  = BF / F;
    int T  = in_sizes[0] / BF;     // mag is [B, T, F]

    // chunk length chosen so one panel (L x F floats) fits the LDS buffer
    int L = PANEL_CAP / F;         // 50 for F=257
    if (L < 1) L = 1;
    if (L > T) L = T;
    int C = (T + L - 1) / L;       // 20 for T=1000

    size_t ws_needed = (size_t)C * BF * sizeof(float);
    if (ws_size < ws_needed) {
        int threads = 256;
        int blocks  = (BF + threads - 1) / threads;
        fns2_fallback<<<blocks, threads, 0, stream>>>(mag, s0, weights, bias,
                                                      alpha, out, B, T, F);
        return;
    }

    float* S = (float*)d_ws;       // [C][BF]

    int blocks = B * C;            // 1280
    fns2_pass1<<<blocks, 256, 0, stream>>>(mag, alpha, S, B, T, F, L, C);
    fns2_pass3<<<blocks, 256, 0, stream>>>(mag, s0, weights, bias, alpha, S,
                                           out, B, T, F, L, C);
}